// Round 10
// baseline (167.381 us; speedup 1.0000x reference)
//
#include <hip/hip_runtime.h>
#include <stdint.h>

#define B_    4
#define C_    256
#define W_    4096
#define DQK_  32
#define NT64_ 64      // 64-wide n tiles per batch
#define TSZ_  16384   // shorts per x0t tile (256c x 64n)

typedef short bf16x8 __attribute__((ext_vector_type(8)));
typedef float f32x4  __attribute__((ext_vector_type(4)));

__device__ __forceinline__ float fexp2f(float x){
#if __has_builtin(__builtin_amdgcn_exp2f)
  return __builtin_amdgcn_exp2f(x);
#else
  return exp2f(x);
#endif
}
__device__ __forceinline__ float frcpf(float x){
#if __has_builtin(__builtin_amdgcn_rcpf)
  return __builtin_amdgcn_rcpf(x);
#else
  return 1.0f / x;
#endif
}
__device__ __forceinline__ unsigned short bf16rn(float f){
  union { float f; uint32_t u; } v; v.f = f;
  uint32_t u = v.u;
  u += 0x7FFFu + ((u >> 16) & 1u);
  return (unsigned short)(u >> 16);
}
__device__ __forceinline__ uint32_t pk2(float a, float b){
  return (uint32_t)bf16rn(a) | ((uint32_t)bf16rn(b) << 16);
}

// ---------------------------------------------------------------------------
// K1: projections -> qf (MFMA-fragment layout) + kT (row-major) + x0t (bf16,
//     swizzled tiles). Lanes map to n, so x0/x1 reads are coalesced AND x0t
//     stores are full 16B/lane line-complete stores (swizzle applied at
//     LDS-flush time). Projection partials cross-wave-reduced via f32 LDS
//     (union'd with the bf16 stage buffer; 37KB -> 2 blocks/CU).
// grid (128,4) block 512: block = 32 n x 256 c; wave cq: c-range cq*32..+32
// (2-way chalf split in-wave, shfl-combined).
// ---------------------------------------------------------------------------
__global__ __launch_bounds__(512) void sa_prep(
    const float* __restrict__ x0, const float* __restrict__ x1,
    const float* __restrict__ wq, const float* __restrict__ bq,
    const float* __restrict__ wk, const float* __restrict__ bk,
    unsigned short* __restrict__ qf, unsigned short* __restrict__ kT,
    unsigned short* __restrict__ x0t)
{
  const int b     = blockIdx.y;
  const int tid   = threadIdx.x;
  const int lane  = tid & 63;
  const int cq    = tid >> 6;            // 0..7
  const int wloc  = lane & 31;           // n within the 32-block
  const int chalf = lane >> 5;           // 0..1
  const int n0    = blockIdx.x * 32;
  const int n     = n0 + wloc;
  const int c0    = cq * 32 + chalf * 16;
  const size_t bw = (size_t)b * ((size_t)C_ * W_) + n;

  __shared__ union {
    unsigned short xs[256 * 32];   // bf16 stage [c][nloc], 16 KB
    float red[8][32][36];          // cross-wave reduce, 36.9 KB
  } sm;

  float accq[DQK_], acck[DQK_];
  #pragma unroll
  for (int d = 0; d < DQK_; ++d){ accq[d] = 0.f; acck[d] = 0.f; }

  for (int i = 0; i < 16; ++i){
    const int c = c0 + i;
    const size_t off = bw + (size_t)c * W_;
    const float v0 = x0[off];
    const float v1 = x1[off];
    sm.xs[c * 32 + wloc] = bf16rn(v0);
    #pragma unroll
    for (int d = 0; d < DQK_; ++d){
      accq[d] = fmaf(wq[d * C_ + c], v0, accq[d]);
      acck[d] = fmaf(wk[d * C_ + c], v1, acck[d]);
    }
  }
  // combine the 2 in-wave c-halves (lane ^ 32 holds same n, other c half)
  #pragma unroll
  for (int d = 0; d < DQK_; ++d){
    accq[d] += __shfl_xor(accq[d], 32);
    acck[d] += __shfl_xor(acck[d], 32);
  }
  __syncthreads();   // xs complete

  // ---- flush x0t: 16B/lane, line-complete coalesced, swizzle at write ----
  {
    unsigned short* xt = x0t + (size_t)(b * NT64_ + (n0 >> 6)) * TSZ_;
    const int j0 = (n0 >> 3) & 7;        // this block's 4 chunks within 64-n rows
    #pragma unroll
    for (int rep = 0; rep < 2; ++rep){
      const int idx = tid + rep * 512;   // 0..1023
      const int row = idx >> 2;          // c 0..255
      const int jl  = idx & 3;
      uint4 v = *(const uint4*)&sm.xs[row * 32 + jl * 8];
      *(uint4*)(xt + row * 64 + (((j0 + jl) ^ (row & 7)) << 3)) = v;
    }
  }
  __syncthreads();   // xs free -> red may overwrite

  // ---- q reduce + fragment-layout pack ----
  if (chalf == 0){
    #pragma unroll
    for (int d4 = 0; d4 < 8; ++d4){
      f32x4 t = { accq[d4*4], accq[d4*4+1], accq[d4*4+2], accq[d4*4+3] };
      *(f32x4*)&sm.red[cq][wloc][d4 * 4] = t;
    }
  }
  __syncthreads();
  if (tid < 256){
    const int nl = tid & 31, dg = tid >> 5;   // dg 0..7 -> d0 = dg*4
    const int d0 = dg * 4;
    float s[4];
    #pragma unroll
    for (int j = 0; j < 4; ++j){
      float t = bq[d0 + j];
      #pragma unroll
      for (int g = 0; g < 8; ++g) t += sm.red[g][nl][d0 + j];
      s[j] = t;
    }
    uint2 pk; pk.x = pk2(s[0], s[1]); pk.y = pk2(s[2], s[3]);
    const int ng = n0 + nl;
    const size_t addr = (((size_t)b * 256 + (ng >> 4)) * 64
                         + (ng & 15) + ((dg >> 1) << 4)) * 8 + (dg & 1) * 4;
    *(uint2*)(qf + addr) = pk;
  }
  __syncthreads();

  // ---- k reduce + row-major pack (scaled) ----
  if (chalf == 0){
    #pragma unroll
    for (int d4 = 0; d4 < 8; ++d4){
      f32x4 t = { acck[d4*4], acck[d4*4+1], acck[d4*4+2], acck[d4*4+3] };
      *(f32x4*)&sm.red[cq][wloc][d4 * 4] = t;
    }
  }
  __syncthreads();
  if (tid < 256){
    const float SCL = 0.0625f * 1.44269504088896340736f; // 1/sqrt(256)*log2(e)
    const int nl = tid & 31, dg = tid >> 5;
    const int d0 = dg * 4;
    float s[4];
    #pragma unroll
    for (int j = 0; j < 4; ++j){
      float t = bk[d0 + j];
      #pragma unroll
      for (int g = 0; g < 8; ++g) t += sm.red[g][nl][d0 + j];
      s[j] = t * SCL;
    }
    uint2 pk; pk.x = pk2(s[0], s[1]); pk.y = pk2(s[2], s[3]);
    *(uint2*)(kT + ((size_t)b * W_ + n0 + nl) * DQK_ + d0) = pk;
  }
}

// ---------------------------------------------------------------------------
// K2: fused denom + attention-write + PV + epilogue.
// Block (b, m-32 tile), 512 thr = 8 waves; wave wid -> (nq=wid>>1, mt=wid&1).
// KEY R8 change: q is register-prefetched ONE ITERATION AHEAD, issued right
// after the barrier and BEFORE STAGE + att-store. The energy MFMA then waits
// vmcnt(5) (its own q only) instead of vmcnt(0) — the only full drain left is
// the per-iter __syncthreads, exactly where STAGE must complete anyway.
// grid 512 (XCD-paired per batch), LDS ~73KB -> 2 blocks/CU.
// ---------------------------------------------------------------------------
__global__ __launch_bounds__(512, 4) void sa_fused(
    const unsigned short* __restrict__ qf, const unsigned short* __restrict__ kT,
    const unsigned short* __restrict__ x0t, const float* __restrict__ x1,
    const float* __restrict__ gamma,
    float* __restrict__ out, float* __restrict__ att)
{
  const int lb = blockIdx.x;
  const int b    = (lb & 7) >> 1;                    // batch -> XCD pair
  const int mblk = ((lb >> 3) << 1) | (lb & 1);      // 0..127
  const int m0 = mblk * 32;
  const int tid = threadIdx.x;
  const int lane = tid & 63;
  const int wid = tid >> 6;                          // 0..7
  const int lr = lane & 15, lg = lane >> 4;
  const int mt = wid & 1, nq = wid >> 1;

  __shared__ __align__(16) unsigned short Abuf[2][TSZ_];   // 2 x 32KB, linear
  __shared__ __align__(16) unsigned short Plds[2][32 * 64];// 2 x 4KB, swizzled
  __shared__ float ssum[8][16];

  const bf16x8 kf = *(const bf16x8*)(kT + ((size_t)b * W_ + m0 + mt * 16 + lr) * DQK_ + lg * 8);
  // per-wave q fragment stream: tile (s*4 + nq), contiguous lane*16B
  const unsigned short* qfw = qf + ((size_t)b * 256 * 64 + (size_t)nq * 64 + lane) * 8;
  const unsigned short* xtb = x0t + (size_t)b * NT64_ * TSZ_;

  #define STAGE(J, BUF) do {                                                      \
    const unsigned short* src_ = xtb + (size_t)(J) * TSZ_ + wid * 2048 + lane * 8;\
    _Pragma("unroll")                                                             \
    for (int k2 = 0; k2 < 4; ++k2){                                               \
      __builtin_amdgcn_global_load_lds(                                           \
        (const __attribute__((address_space(1))) unsigned int*)(src_ + k2 * 512), \
        (__attribute__((address_space(3))) unsigned int*)(&Abuf[BUF][wid * 2048 + k2 * 512]), \
        16, 0, 0);                                                                \
    }                                                                             \
  } while(0)

  STAGE(0, 0);   // drained at pass-1's first q wait (harmless) / ssum barrier

  // ---- pass 1: denominators (energy-only), q prefetched 1 iter ahead ----
  float ps = 0.f;
  {
    bf16x8 qv = *(const bf16x8*)qfw;
    for (int s = 0; s < NT64_; ++s){
      bf16x8 qn = *(const bf16x8*)(qfw + (size_t)((s + 1) & (NT64_ - 1)) * 2048);
      f32x4 e = __builtin_amdgcn_mfma_f32_16x16x32_bf16(qv, kf, (f32x4){0.f,0.f,0.f,0.f}, 0, 0, 0);
      ps += fexp2f(e[0]) + fexp2f(e[1]) + fexp2f(e[2]) + fexp2f(e[3]);
      qv = qn;
    }
  }
  ps += __shfl_xor(ps, 16);
  ps += __shfl_xor(ps, 32);
  if (lane < 16) ssum[wid][lane] = ps;     // lanes 0..15: lg==0, lr==lane
  __syncthreads();
  const float is = frcpf(ssum[mt][lr] + ssum[mt + 2][lr] + ssum[mt + 4][lr] + ssum[mt + 6][lr]);

  // ---- pass 2 ----
  f32x4 acc[2][2];
  #pragma unroll
  for (int ct = 0; ct < 2; ++ct)
    #pragma unroll
    for (int m2 = 0; m2 < 2; ++m2) acc[ct][m2] = (f32x4){0.f,0.f,0.f,0.f};

  const int mlocP = mt * 16 + lr;
  const int pw_off = mlocP * 64
      + (((nq * 2 + (lg >> 1)) ^ (mlocP & 7)) << 3) + (lg & 1) * 4;
  float* attp = att + ((size_t)b * W_ + m0 + mt * 16 + lr) * W_ + nq * 16 + lg * 4;

  bf16x8 qv = *(const bf16x8*)qfw;         // q for s=0
  for (int s = 0; s < NT64_; ++s){
    const int cur = s & 1;
    const int n0 = s * 64;

    // energy quarter -> P[cur] (qv was prefetched last iter: waits vmcnt(5))
    f32x4 e = __builtin_amdgcn_mfma_f32_16x16x32_bf16(qv, kf, (f32x4){0.f,0.f,0.f,0.f}, 0, 0, 0);
    f32x4 p;
    #pragma unroll
    for (int r = 0; r < 4; ++r) p[r] = fexp2f(e[r]) * is;
    uint2 pv; pv.x = pk2(p[0], p[1]); pv.y = pk2(p[2], p[3]);
    *(uint2*)(&Plds[cur][0] + pw_off) = pv;

    __syncthreads();   // the ONLY vmcnt(0) point: P[cur] visible, STAGE(s) drained

    // prefetch q for s+1 FIRST (so later VMEM ops keep its wait > 0)
    qv = *(const bf16x8*)(qfw + (size_t)((s + 1) & (NT64_ - 1)) * 2048);
    STAGE((s + 1) & (NT64_ - 1), cur ^ 1);                  // flies until next barrier
    __builtin_nontemporal_store(p, (f32x4*)(attp + n0));

    // PV: A = x0 rows c (own swizzled Abuf rows), B = P[cur] (swizzled)
    const unsigned short* Pb = &Plds[cur][0];
    bf16x8 pf[2][2], af[2][2];
    __builtin_amdgcn_s_setprio(1);
    #pragma unroll
    for (int m2 = 0; m2 < 2; ++m2){
      const int prow = m2 * 16 + lr;
      #pragma unroll
      for (int ks = 0; ks < 2; ++ks)
        pf[m2][ks] = *(const bf16x8*)&Pb[prow * 64 + (((ks * 4 + lg) ^ (prow & 7)) << 3)];
    }
    #pragma unroll
    for (int ct = 0; ct < 2; ++ct){
      const int crow = wid * 32 + ct * 16 + lr;
      #pragma unroll
      for (int ks = 0; ks < 2; ++ks)
        af[ct][ks] = *(const bf16x8*)&Abuf[cur][crow * 64 + (((ks * 4 + lg) ^ (crow & 7)) << 3)];
    }
    #pragma unroll
    for (int ct = 0; ct < 2; ++ct)
      #pragma unroll
      for (int m2 = 0; m2 < 2; ++m2){
        acc[ct][m2] = __builtin_amdgcn_mfma_f32_16x16x32_bf16(af[ct][0], pf[m2][0], acc[ct][m2], 0, 0, 0);
        acc[ct][m2] = __builtin_amdgcn_mfma_f32_16x16x32_bf16(af[ct][1], pf[m2][1], acc[ct][m2], 0, 0, 0);
      }
    __builtin_amdgcn_s_setprio(0);
  }
  #undef STAGE

  // ---- epilogue: out[c][m] = gamma*acc + x1 (nontemporal both ways) ----
  const float g = gamma[0];
  const float* x1b = x1 + (size_t)b * C_ * W_;
  float* outb = out + (size_t)b * C_ * W_;
  #pragma unroll
  for (int ct = 0; ct < 2; ++ct)
    #pragma unroll
    for (int m2 = 0; m2 < 2; ++m2)
      #pragma unroll
      for (int r = 0; r < 4; ++r){
        const int c = wid * 32 + ct * 16 + lg * 4 + r;
        const size_t idx = (size_t)c * W_ + m0 + m2 * 16 + lr;
        const float xv = __builtin_nontemporal_load(&x1b[idx]);
        __builtin_nontemporal_store(fmaf(g, acc[ct][m2][r], xv), &outb[idx]);
      }
}

extern "C" void kernel_launch(void* const* d_in, const int* in_sizes, int n_in,
                              void* d_out, int out_size, void* d_ws, size_t ws_size,
                              hipStream_t stream)
{
  (void)in_sizes; (void)n_in; (void)out_size; (void)ws_size;
  const float* x0    = (const float*)d_in[0];
  const float* x1    = (const float*)d_in[1];
  const float* wq    = (const float*)d_in[2];
  const float* bq    = (const float*)d_in[3];
  const float* wk    = (const float*)d_in[4];
  const float* bk    = (const float*)d_in[5];
  const float* gamma = (const float*)d_in[6];

  unsigned short* qf  = (unsigned short*)d_ws;                   // 1 MB (fragment layout)
  unsigned short* kT  = qf + (size_t)B_ * W_ * DQK_;             // 1 MB
  unsigned short* x0t = kT + (size_t)B_ * W_ * DQK_;             // 8 MB swizzled tiles

  float* out = (float*)d_out;                                    // [B][C][W]
  float* att = out + (size_t)B_ * C_ * W_;                       // [B][W][W]

  sa_prep <<<dim3(128, 4), 512, 0, stream>>>(x0, x1, wq, bq, wk, bk, qf, kT, x0t);
  sa_fused<<<512, 512, 0, stream>>>(qf, kT, x0t, x1, gamma, out, att);
}

// Round 11
// 160.930 us; speedup vs baseline: 1.0401x; 1.0401x over previous
//
#include <hip/hip_runtime.h>
#include <stdint.h>

#define B_    4
#define C_    256
#define W_    4096
#define DQK_  32
#define NT64_ 64      // 64-wide n tiles per batch
#define TSZ_  16384   // shorts per x0t tile (256c x 64n)

typedef short bf16x8 __attribute__((ext_vector_type(8)));
typedef float f32x4  __attribute__((ext_vector_type(4)));

__device__ __forceinline__ float fexp2f(float x){
#if __has_builtin(__builtin_amdgcn_exp2f)
  return __builtin_amdgcn_exp2f(x);
#else
  return exp2f(x);
#endif
}
__device__ __forceinline__ float frcpf(float x){
#if __has_builtin(__builtin_amdgcn_rcpf)
  return __builtin_amdgcn_rcpf(x);
#else
  return 1.0f / x;
#endif
}
__device__ __forceinline__ unsigned short bf16rn(float f){
  union { float f; uint32_t u; } v; v.f = f;
  uint32_t u = v.u;
  u += 0x7FFFu + ((u >> 16) & 1u);
  return (unsigned short)(u >> 16);
}
__device__ __forceinline__ uint32_t pk2(float a, float b){
  return (uint32_t)bf16rn(a) | ((uint32_t)bf16rn(b) << 16);
}

// ---------------------------------------------------------------------------
// K1: projections -> qf (MFMA-fragment layout) + kT (row-major) + x0t (bf16,
//     swizzled tiles). Lanes map to n: coalesced x0/x1 reads, line-complete
//     x0t flush via LDS stage. Unchanged from R8.
// ---------------------------------------------------------------------------
__global__ __launch_bounds__(512) void sa_prep(
    const float* __restrict__ x0, const float* __restrict__ x1,
    const float* __restrict__ wq, const float* __restrict__ bq,
    const float* __restrict__ wk, const float* __restrict__ bk,
    unsigned short* __restrict__ qf, unsigned short* __restrict__ kT,
    unsigned short* __restrict__ x0t)
{
  const int b     = blockIdx.y;
  const int tid   = threadIdx.x;
  const int lane  = tid & 63;
  const int cq    = tid >> 6;            // 0..7
  const int wloc  = lane & 31;           // n within the 32-block
  const int chalf = lane >> 5;           // 0..1
  const int n0    = blockIdx.x * 32;
  const int n     = n0 + wloc;
  const int c0    = cq * 32 + chalf * 16;
  const size_t bw = (size_t)b * ((size_t)C_ * W_) + n;

  __shared__ union {
    unsigned short xs[256 * 32];   // bf16 stage [c][nloc], 16 KB
    float red[8][32][36];          // cross-wave reduce, 36.9 KB
  } sm;

  float accq[DQK_], acck[DQK_];
  #pragma unroll
  for (int d = 0; d < DQK_; ++d){ accq[d] = 0.f; acck[d] = 0.f; }

  for (int i = 0; i < 16; ++i){
    const int c = c0 + i;
    const size_t off = bw + (size_t)c * W_;
    const float v0 = x0[off];
    const float v1 = x1[off];
    sm.xs[c * 32 + wloc] = bf16rn(v0);
    #pragma unroll
    for (int d = 0; d < DQK_; ++d){
      accq[d] = fmaf(wq[d * C_ + c], v0, accq[d]);
      acck[d] = fmaf(wk[d * C_ + c], v1, acck[d]);
    }
  }
  #pragma unroll
  for (int d = 0; d < DQK_; ++d){
    accq[d] += __shfl_xor(accq[d], 32);
    acck[d] += __shfl_xor(acck[d], 32);
  }
  __syncthreads();   // xs complete

  {
    unsigned short* xt = x0t + (size_t)(b * NT64_ + (n0 >> 6)) * TSZ_;
    const int j0 = (n0 >> 3) & 7;
    #pragma unroll
    for (int rep = 0; rep < 2; ++rep){
      const int idx = tid + rep * 512;
      const int row = idx >> 2;
      const int jl  = idx & 3;
      uint4 v = *(const uint4*)&sm.xs[row * 32 + jl * 8];
      *(uint4*)(xt + row * 64 + (((j0 + jl) ^ (row & 7)) << 3)) = v;
    }
  }
  __syncthreads();   // xs free -> red may overwrite

  if (chalf == 0){
    #pragma unroll
    for (int d4 = 0; d4 < 8; ++d4){
      f32x4 t = { accq[d4*4], accq[d4*4+1], accq[d4*4+2], accq[d4*4+3] };
      *(f32x4*)&sm.red[cq][wloc][d4 * 4] = t;
    }
  }
  __syncthreads();
  if (tid < 256){
    const int nl = tid & 31, dg = tid >> 5;
    const int d0 = dg * 4;
    float s[4];
    #pragma unroll
    for (int j = 0; j < 4; ++j){
      float t = bq[d0 + j];
      #pragma unroll
      for (int g = 0; g < 8; ++g) t += sm.red[g][nl][d0 + j];
      s[j] = t;
    }
    uint2 pk; pk.x = pk2(s[0], s[1]); pk.y = pk2(s[2], s[3]);
    const int ng = n0 + nl;
    const size_t addr = (((size_t)b * 256 + (ng >> 4)) * 64
                         + (ng & 15) + ((dg >> 1) << 4)) * 8 + (dg & 1) * 4;
    *(uint2*)(qf + addr) = pk;
  }
  __syncthreads();

  if (chalf == 0){
    #pragma unroll
    for (int d4 = 0; d4 < 8; ++d4){
      f32x4 t = { acck[d4*4], acck[d4*4+1], acck[d4*4+2], acck[d4*4+3] };
      *(f32x4*)&sm.red[cq][wloc][d4 * 4] = t;
    }
  }
  __syncthreads();
  if (tid < 256){
    const float SCL = 0.0625f * 1.44269504088896340736f; // 1/sqrt(256)*log2(e)
    const int nl = tid & 31, dg = tid >> 5;
    const int d0 = dg * 4;
    float s[4];
    #pragma unroll
    for (int j = 0; j < 4; ++j){
      float t = bk[d0 + j];
      #pragma unroll
      for (int g = 0; g < 8; ++g) t += sm.red[g][nl][d0 + j];
      s[j] = t * SCL;
    }
    uint2 pk; pk.x = pk2(s[0], s[1]); pk.y = pk2(s[2], s[3]);
    *(uint2*)(kT + ((size_t)b * W_ + n0 + nl) * DQK_ + d0) = pk;
  }
}

// ---------------------------------------------------------------------------
// K2: fused denom + attention-write + PV + epilogue.
// R11 KEY CHANGE: pass-2 uses a RELAXED barrier — s_waitcnt vmcnt(1) +
// lgkmcnt(0) + raw s_barrier — instead of __syncthreads (which drains
// vmcnt(0) and thus waits for the att-store ACK every iteration, ~1000s of
// cycles under streaming-write pressure). VMEM issue order is pinned
// [qv prefetch, STAGE x8, sched_barrier, att store] so the store is always
// the single NEWEST op: vmcnt(1) completes the STAGE loads (Abuf
// correctness) while the store ack floats for a full iteration.
// P double-buffered: write P[cur] < barrier(s) < read P[cur] < barrier(s+1)
// < next write to P[cur] at s+2 -> one barrier per iter is safe.
// Abuf rows are strictly per-wave (staged and read by the same wave).
// grid 512 (XCD-paired per batch), LDS ~73KB -> 2 blocks/CU.
// ---------------------------------------------------------------------------
__global__ __launch_bounds__(512, 4) void sa_fused(
    const unsigned short* __restrict__ qf, const unsigned short* __restrict__ kT,
    const unsigned short* __restrict__ x0t, const float* __restrict__ x1,
    const float* __restrict__ gamma,
    float* __restrict__ out, float* __restrict__ att)
{
  const int lb = blockIdx.x;
  const int b    = (lb & 7) >> 1;                    // batch -> XCD pair
  const int mblk = ((lb >> 3) << 1) | (lb & 1);      // 0..127
  const int m0 = mblk * 32;
  const int tid = threadIdx.x;
  const int lane = tid & 63;
  const int wid = tid >> 6;                          // 0..7
  const int lr = lane & 15, lg = lane >> 4;
  const int mt = wid & 1, nq = wid >> 1;

  __shared__ __align__(16) unsigned short Abuf[2][TSZ_];   // 2 x 32KB, linear
  __shared__ __align__(16) unsigned short Plds[2][32 * 64];// 2 x 4KB, swizzled
  __shared__ float ssum[8][16];

  const bf16x8 kf = *(const bf16x8*)(kT + ((size_t)b * W_ + m0 + mt * 16 + lr) * DQK_ + lg * 8);
  const unsigned short* qfw = qf + ((size_t)b * 256 * 64 + (size_t)nq * 64 + lane) * 8;
  const unsigned short* xtb = x0t + (size_t)b * NT64_ * TSZ_;

  #define STAGE(J, BUF) do {                                                      \
    const unsigned short* src_ = xtb + (size_t)(J) * TSZ_ + wid * 2048 + lane * 8;\
    _Pragma("unroll")                                                             \
    for (int k2 = 0; k2 < 4; ++k2){                                               \
      __builtin_amdgcn_global_load_lds(                                           \
        (const __attribute__((address_space(1))) unsigned int*)(src_ + k2 * 512), \
        (__attribute__((address_space(3))) unsigned int*)(&Abuf[BUF][wid * 2048 + k2 * 512]), \
        16, 0, 0);                                                                \
    }                                                                             \
  } while(0)

  STAGE(0, 0);   // drained at the ssum __syncthreads

  // ---- pass 1: denominators (energy-only), q prefetched 1 iter ahead ----
  float ps = 0.f;
  {
    bf16x8 qv = *(const bf16x8*)qfw;
    for (int s = 0; s < NT64_; ++s){
      bf16x8 qn = *(const bf16x8*)(qfw + (size_t)((s + 1) & (NT64_ - 1)) * 2048);
      f32x4 e = __builtin_amdgcn_mfma_f32_16x16x32_bf16(qv, kf, (f32x4){0.f,0.f,0.f,0.f}, 0, 0, 0);
      ps += fexp2f(e[0]) + fexp2f(e[1]) + fexp2f(e[2]) + fexp2f(e[3]);
      qv = qn;
    }
  }
  ps += __shfl_xor(ps, 16);
  ps += __shfl_xor(ps, 32);
  if (lane < 16) ssum[wid][lane] = ps;
  __syncthreads();   // full drain here is fine (once)
  const float is = frcpf(ssum[mt][lr] + ssum[mt + 2][lr] + ssum[mt + 4][lr] + ssum[mt + 6][lr]);

  // ---- pass 2 ----
  f32x4 acc[2][2];
  #pragma unroll
  for (int ct = 0; ct < 2; ++ct)
    #pragma unroll
    for (int m2 = 0; m2 < 2; ++m2) acc[ct][m2] = (f32x4){0.f,0.f,0.f,0.f};

  const int mlocP = mt * 16 + lr;
  const int pw_off = mlocP * 64
      + (((nq * 2 + (lg >> 1)) ^ (mlocP & 7)) << 3) + (lg & 1) * 4;
  float* attp = att + ((size_t)b * W_ + m0 + mt * 16 + lr) * W_ + nq * 16 + lg * 4;

  bf16x8 qv = *(const bf16x8*)qfw;         // q for s=0
  for (int s = 0; s < NT64_; ++s){
    const int cur = s & 1;
    const int n0 = s * 64;

    // energy quarter -> P[cur] (compiler-inserted wait covers qv only)
    f32x4 e = __builtin_amdgcn_mfma_f32_16x16x32_bf16(qv, kf, (f32x4){0.f,0.f,0.f,0.f}, 0, 0, 0);
    f32x4 p;
    #pragma unroll
    for (int r = 0; r < 4; ++r) p[r] = fexp2f(e[r]) * is;
    uint2 pv; pv.x = pk2(p[0], p[1]); pv.y = pk2(p[2], p[3]);
    *(uint2*)(&Plds[cur][0] + pw_off) = pv;

    // RELAXED barrier: complete STAGE(s) (8 loads) but let the newest VMEM op
    // (att store of iter s-1) stay in flight; P visibility via lgkmcnt(0).
    asm volatile("s_waitcnt vmcnt(1)\n\t"
                 "s_waitcnt lgkmcnt(0)" ::: "memory");
    __builtin_amdgcn_sched_barrier(0);
    __builtin_amdgcn_s_barrier();
    __builtin_amdgcn_sched_barrier(0);

    // VMEM issue order this iter: qv(s+1), STAGE(s+1) x8, [pin], att store(s)
    qv = *(const bf16x8*)(qfw + (size_t)((s + 1) & (NT64_ - 1)) * 2048);
    STAGE((s + 1) & (NT64_ - 1), cur ^ 1);
    __builtin_amdgcn_sched_barrier(0);     // keep store NEWEST (after STAGE)
    __builtin_nontemporal_store(p, (f32x4*)(attp + n0));

    // PV: A = x0 rows c (own swizzled Abuf rows), B = P[cur] (swizzled)
    const unsigned short* Pb = &Plds[cur][0];
    bf16x8 pf[2][2], af[2][2];
    __builtin_amdgcn_s_setprio(1);
    #pragma unroll
    for (int m2 = 0; m2 < 2; ++m2){
      const int prow = m2 * 16 + lr;
      #pragma unroll
      for (int ks = 0; ks < 2; ++ks)
        pf[m2][ks] = *(const bf16x8*)&Pb[prow * 64 + (((ks * 4 + lg) ^ (prow & 7)) << 3)];
    }
    #pragma unroll
    for (int ct = 0; ct < 2; ++ct){
      const int crow = wid * 32 + ct * 16 + lr;
      #pragma unroll
      for (int ks = 0; ks < 2; ++ks)
        af[ct][ks] = *(const bf16x8*)&Abuf[cur][crow * 64 + (((ks * 4 + lg) ^ (crow & 7)) << 3)];
    }
    #pragma unroll
    for (int ct = 0; ct < 2; ++ct)
      #pragma unroll
      for (int m2 = 0; m2 < 2; ++m2){
        acc[ct][m2] = __builtin_amdgcn_mfma_f32_16x16x32_bf16(af[ct][0], pf[m2][0], acc[ct][m2], 0, 0, 0);
        acc[ct][m2] = __builtin_amdgcn_mfma_f32_16x16x32_bf16(af[ct][1], pf[m2][1], acc[ct][m2], 0, 0, 0);
      }
    __builtin_amdgcn_s_setprio(0);
  }
  #undef STAGE

  // ---- epilogue: out[c][m] = gamma*acc + x1 (nontemporal both ways) ----
  const float g = gamma[0];
  const float* x1b = x1 + (size_t)b * C_ * W_;
  float* outb = out + (size_t)b * C_ * W_;
  #pragma unroll
  for (int ct = 0; ct < 2; ++ct)
    #pragma unroll
    for (int m2 = 0; m2 < 2; ++m2)
      #pragma unroll
      for (int r = 0; r < 4; ++r){
        const int c = wid * 32 + ct * 16 + lg * 4 + r;
        const size_t idx = (size_t)c * W_ + m0 + m2 * 16 + lr;
        const float xv = __builtin_nontemporal_load(&x1b[idx]);
        __builtin_nontemporal_store(fmaf(g, acc[ct][m2][r], xv), &outb[idx]);
      }
}

extern "C" void kernel_launch(void* const* d_in, const int* in_sizes, int n_in,
                              void* d_out, int out_size, void* d_ws, size_t ws_size,
                              hipStream_t stream)
{
  (void)in_sizes; (void)n_in; (void)out_size; (void)ws_size;
  const float* x0    = (const float*)d_in[0];
  const float* x1    = (const float*)d_in[1];
  const float* wq    = (const float*)d_in[2];
  const float* bq    = (const float*)d_in[3];
  const float* wk    = (const float*)d_in[4];
  const float* bk    = (const float*)d_in[5];
  const float* gamma = (const float*)d_in[6];

  unsigned short* qf  = (unsigned short*)d_ws;                   // 1 MB (fragment layout)
  unsigned short* kT  = qf + (size_t)B_ * W_ * DQK_;             // 1 MB
  unsigned short* x0t = kT + (size_t)B_ * W_ * DQK_;             // 8 MB swizzled tiles

  float* out = (float*)d_out;                                    // [B][C][W]
  float* att = out + (size_t)B_ * C_ * W_;                       // [B][W][W]

  sa_prep <<<dim3(128, 4), 512, 0, stream>>>(x0, x1, wq, bq, wk, bk, qf, kT, x0t);
  sa_fused<<<512, 512, 0, stream>>>(qf, kT, x0t, x1, gamma, out, att);
}

// Round 12
// 158.412 us; speedup vs baseline: 1.0566x; 1.0159x over previous
//
#include <hip/hip_runtime.h>
#include <stdint.h>

#define B_    4
#define C_    256
#define W_    4096
#define DQK_  32
#define NT64_ 64      // 64-wide n tiles per batch
#define TSZ_  16384   // shorts per x0t tile (256c x 64n)

typedef short bf16x8 __attribute__((ext_vector_type(8)));
typedef float f32x4  __attribute__((ext_vector_type(4)));

__device__ __forceinline__ float fexp2f(float x){
#if __has_builtin(__builtin_amdgcn_exp2f)
  return __builtin_amdgcn_exp2f(x);
#else
  return exp2f(x);
#endif
}
__device__ __forceinline__ float frcpf(float x){
#if __has_builtin(__builtin_amdgcn_rcpf)
  return __builtin_amdgcn_rcpf(x);
#else
  return 1.0f / x;
#endif
}
// single-instruction packed f32->bf16 (RTNE) — replaces manual bit-math packs
__device__ __forceinline__ uint32_t cvtpk(float a, float b){
  uint32_t r;
  asm("v_cvt_pk_bf16_f32 %0, %1, %2" : "=v"(r) : "v"(a), "v"(b));
  return r;
}
__device__ __forceinline__ unsigned short bf16c(float f){
  return (unsigned short)cvtpk(f, f);
}

// ---------------------------------------------------------------------------
// K1: projections -> qf (MFMA-fragment layout) + kT (row-major) + x0t (bf16,
//     swizzled tiles). Lanes map to n: coalesced x0/x1 reads, line-complete
//     x0t flush via LDS stage. Same structure as R8-R11; packs via cvt_pk.
// ---------------------------------------------------------------------------
__global__ __launch_bounds__(512) void sa_prep(
    const float* __restrict__ x0, const float* __restrict__ x1,
    const float* __restrict__ wq, const float* __restrict__ bq,
    const float* __restrict__ wk, const float* __restrict__ bk,
    unsigned short* __restrict__ qf, unsigned short* __restrict__ kT,
    unsigned short* __restrict__ x0t)
{
  const int b     = blockIdx.y;
  const int tid   = threadIdx.x;
  const int lane  = tid & 63;
  const int cq    = tid >> 6;            // 0..7
  const int wloc  = lane & 31;           // n within the 32-block
  const int chalf = lane >> 5;           // 0..1
  const int n0    = blockIdx.x * 32;
  const int n     = n0 + wloc;
  const int c0    = cq * 32 + chalf * 16;
  const size_t bw = (size_t)b * ((size_t)C_ * W_) + n;

  __shared__ union {
    unsigned short xs[256 * 32];   // bf16 stage [c][nloc], 16 KB
    float red[8][32][36];          // cross-wave reduce, 36.9 KB
  } sm;

  float accq[DQK_], acck[DQK_];
  #pragma unroll
  for (int d = 0; d < DQK_; ++d){ accq[d] = 0.f; acck[d] = 0.f; }

  for (int i = 0; i < 16; ++i){
    const int c = c0 + i;
    const size_t off = bw + (size_t)c * W_;
    const float v0 = x0[off];
    const float v1 = x1[off];
    sm.xs[c * 32 + wloc] = bf16c(v0);
    #pragma unroll
    for (int d = 0; d < DQK_; ++d){
      accq[d] = fmaf(wq[d * C_ + c], v0, accq[d]);
      acck[d] = fmaf(wk[d * C_ + c], v1, acck[d]);
    }
  }
  #pragma unroll
  for (int d = 0; d < DQK_; ++d){
    accq[d] += __shfl_xor(accq[d], 32);
    acck[d] += __shfl_xor(acck[d], 32);
  }
  __syncthreads();   // xs complete

  {
    unsigned short* xt = x0t + (size_t)(b * NT64_ + (n0 >> 6)) * TSZ_;
    const int j0 = (n0 >> 3) & 7;
    #pragma unroll
    for (int rep = 0; rep < 2; ++rep){
      const int idx = tid + rep * 512;
      const int row = idx >> 2;
      const int jl  = idx & 3;
      uint4 v = *(const uint4*)&sm.xs[row * 32 + jl * 8];
      *(uint4*)(xt + row * 64 + (((j0 + jl) ^ (row & 7)) << 3)) = v;
    }
  }
  __syncthreads();   // xs free -> red may overwrite

  if (chalf == 0){
    #pragma unroll
    for (int d4 = 0; d4 < 8; ++d4){
      f32x4 t = { accq[d4*4], accq[d4*4+1], accq[d4*4+2], accq[d4*4+3] };
      *(f32x4*)&sm.red[cq][wloc][d4 * 4] = t;
    }
  }
  __syncthreads();
  if (tid < 256){
    const int nl = tid & 31, dg = tid >> 5;
    const int d0 = dg * 4;
    float s[4];
    #pragma unroll
    for (int j = 0; j < 4; ++j){
      float t = bq[d0 + j];
      #pragma unroll
      for (int g = 0; g < 8; ++g) t += sm.red[g][nl][d0 + j];
      s[j] = t;
    }
    uint2 pk; pk.x = cvtpk(s[0], s[1]); pk.y = cvtpk(s[2], s[3]);
    const int ng = n0 + nl;
    const size_t addr = (((size_t)b * 256 + (ng >> 4)) * 64
                         + (ng & 15) + ((dg >> 1) << 4)) * 8 + (dg & 1) * 4;
    *(uint2*)(qf + addr) = pk;
  }
  __syncthreads();

  if (chalf == 0){
    #pragma unroll
    for (int d4 = 0; d4 < 8; ++d4){
      f32x4 t = { acck[d4*4], acck[d4*4+1], acck[d4*4+2], acck[d4*4+3] };
      *(f32x4*)&sm.red[cq][wloc][d4 * 4] = t;
    }
  }
  __syncthreads();
  if (tid < 256){
    const float SCL = 0.0625f * 1.44269504088896340736f; // 1/sqrt(256)*log2(e)
    const int nl = tid & 31, dg = tid >> 5;
    const int d0 = dg * 4;
    float s[4];
    #pragma unroll
    for (int j = 0; j < 4; ++j){
      float t = bk[d0 + j];
      #pragma unroll
      for (int g = 0; g < 8; ++g) t += sm.red[g][nl][d0 + j];
      s[j] = t * SCL;
    }
    uint2 pk; pk.x = cvtpk(s[0], s[1]); pk.y = cvtpk(s[2], s[3]);
    *(uint2*)(kT + ((size_t)b * W_ + n0 + nl) * DQK_ + d0) = pk;
  }
}

// ---------------------------------------------------------------------------
// K2: fused denom + attention-write + PV + epilogue.
// R12: VALU strength-reduction. All DS swizzle offsets precomputed as loop-
// invariant ints; qv/STAGE/att become running pointers (constant increments,
// uniform wrap); P pack via v_cvt_pk_bf16_f32. Sync structure = R11 verbatim
// (relaxed barrier: vmcnt(1)+lgkmcnt(0)+s_barrier; store kept newest VMEM op).
// grid 512 (XCD-paired per batch), LDS ~73KB.
// ---------------------------------------------------------------------------
__global__ __launch_bounds__(512, 4) void sa_fused(
    const unsigned short* __restrict__ qf, const unsigned short* __restrict__ kT,
    const unsigned short* __restrict__ x0t, const float* __restrict__ x1,
    const float* __restrict__ gamma,
    float* __restrict__ out, float* __restrict__ att)
{
  const int lb = blockIdx.x;
  const int b    = (lb & 7) >> 1;                    // batch -> XCD pair
  const int mblk = ((lb >> 3) << 1) | (lb & 1);      // 0..127
  const int m0 = mblk * 32;
  const int tid = threadIdx.x;
  const int lane = tid & 63;
  const int wid = tid >> 6;                          // 0..7
  const int lr = lane & 15, lg = lane >> 4;
  const int mt = wid & 1, nq = wid >> 1;

  __shared__ __align__(16) unsigned short Abuf[2][TSZ_];   // 2 x 32KB, linear
  __shared__ __align__(16) unsigned short Plds[2][32 * 64];// 2 x 4KB, swizzled
  __shared__ float ssum[8][16];

  const bf16x8 kf = *(const bf16x8*)(kT + ((size_t)b * W_ + m0 + mt * 16 + lr) * DQK_ + lg * 8);
  const unsigned short* qfw = qf + ((size_t)b * 256 * 64 + (size_t)nq * 64 + lane) * 8;
  const unsigned short* xtb = x0t + (size_t)b * NT64_ * TSZ_;
  const unsigned short* sbase = xtb + wid * 2048 + lane * 8;   // lane-resolved STAGE src
  unsigned short* adst = &Abuf[0][wid * 2048];                 // per-wave LDS dest (buf 0)

  #define STAGEP(SRC, BUF) do {                                                   \
    _Pragma("unroll")                                                             \
    for (int k2 = 0; k2 < 4; ++k2){                                               \
      __builtin_amdgcn_global_load_lds(                                           \
        (const __attribute__((address_space(1))) unsigned int*)((SRC) + k2 * 512),\
        (__attribute__((address_space(3))) unsigned int*)(adst + (BUF) * TSZ_ + k2 * 512), \
        16, 0, 0);                                                                \
    }                                                                             \
  } while(0)

  STAGEP(sbase, 0);   // tile 0; drained at the ssum __syncthreads

  // ---- pass 1: denominators (energy-only), q prefetched 1 iter ahead ----
  float ps = 0.f;
  {
    const unsigned short* qp = qfw + 2048;   // tile for s+1
    bf16x8 qv = *(const bf16x8*)qfw;
    for (int s = 0; s < NT64_; ++s){
      bf16x8 qn = *(const bf16x8*)qp;
      qp = (s == NT64_ - 2) ? qfw : (qp + 2048);
      f32x4 e = __builtin_amdgcn_mfma_f32_16x16x32_bf16(qv, kf, (f32x4){0.f,0.f,0.f,0.f}, 0, 0, 0);
      ps += fexp2f(e[0]) + fexp2f(e[1]) + fexp2f(e[2]) + fexp2f(e[3]);
      qv = qn;
    }
  }
  ps += __shfl_xor(ps, 16);
  ps += __shfl_xor(ps, 32);
  if (lane < 16) ssum[wid][lane] = ps;
  __syncthreads();   // full drain here is fine (once)
  const float is = frcpf(ssum[mt][lr] + ssum[mt + 2][lr] + ssum[mt + 4][lr] + ssum[mt + 6][lr]);

  // ---- pass 2 ----
  f32x4 acc[2][2];
  #pragma unroll
  for (int ct = 0; ct < 2; ++ct)
    #pragma unroll
    for (int m2 = 0; m2 < 2; ++m2) acc[ct][m2] = (f32x4){0.f,0.f,0.f,0.f};

  // loop-invariant DS offsets (shorts), selected by cur at use
  const int mlocP = mt * 16 + lr;
  const int pw_off = mlocP * 64
      + (((nq * 2 + (lg >> 1)) ^ (mlocP & 7)) << 3) + (lg & 1) * 4;
  int afo[2][2], pfo[2][2];
  #pragma unroll
  for (int ct = 0; ct < 2; ++ct){
    const int crow = wid * 32 + ct * 16 + lr;
    #pragma unroll
    for (int ks = 0; ks < 2; ++ks)
      afo[ct][ks] = crow * 64 + (((ks * 4 + lg) ^ (crow & 7)) << 3);
  }
  #pragma unroll
  for (int m2 = 0; m2 < 2; ++m2){
    const int prow = m2 * 16 + lr;
    #pragma unroll
    for (int ks = 0; ks < 2; ++ks)
      pfo[m2][ks] = prow * 64 + (((ks * 4 + lg) ^ (prow & 7)) << 3);
  }

  // running pointers (constant increments; uniform wrap)
  const unsigned short* qp = qfw + 2048;        // q tile for s+1
  const unsigned short* srcp = sbase + TSZ_;    // x0t tile for s+1
  float* attw = att + ((size_t)b * W_ + m0 + mt * 16 + lr) * W_ + nq * 16 + lg * 4;

  bf16x8 qv = *(const bf16x8*)qfw;              // q for s=0
  for (int s = 0; s < NT64_; ++s){
    const int cur = s & 1;

    // energy quarter -> P[cur] (compiler wait covers qv only)
    f32x4 e = __builtin_amdgcn_mfma_f32_16x16x32_bf16(qv, kf, (f32x4){0.f,0.f,0.f,0.f}, 0, 0, 0);
    f32x4 p;
    #pragma unroll
    for (int r = 0; r < 4; ++r) p[r] = fexp2f(e[r]) * is;
    uint2 pv; pv.x = cvtpk(p[0], p[1]); pv.y = cvtpk(p[2], p[3]);
    *(uint2*)(&Plds[cur][0] + pw_off) = pv;

    // RELAXED barrier (R11): complete STAGE(s), let att store(s-1) float.
    asm volatile("s_waitcnt vmcnt(1)\n\t"
                 "s_waitcnt lgkmcnt(0)" ::: "memory");
    __builtin_amdgcn_sched_barrier(0);
    __builtin_amdgcn_s_barrier();
    __builtin_amdgcn_sched_barrier(0);

    // VMEM issue order: qv(s+1), STAGE(s+1) x4, [pin], att store(s)
    qv = *(const bf16x8*)qp;
    qp = (s == NT64_ - 2) ? qfw : (qp + 2048);
    STAGEP(srcp, cur ^ 1);
    srcp = (s == NT64_ - 2) ? sbase : (srcp + TSZ_);
    __builtin_amdgcn_sched_barrier(0);     // keep store NEWEST (after STAGE)
    __builtin_nontemporal_store(p, (f32x4*)attw);
    attw += 64;

    // PV: A = x0 rows c (own Abuf rows), B = P[cur]
    const unsigned short* Ab = &Abuf[cur][0];
    const unsigned short* Pb = &Plds[cur][0];
    bf16x8 pf[2][2], af[2][2];
    __builtin_amdgcn_s_setprio(1);
    #pragma unroll
    for (int m2 = 0; m2 < 2; ++m2)
      #pragma unroll
      for (int ks = 0; ks < 2; ++ks)
        pf[m2][ks] = *(const bf16x8*)(Pb + pfo[m2][ks]);
    #pragma unroll
    for (int ct = 0; ct < 2; ++ct)
      #pragma unroll
      for (int ks = 0; ks < 2; ++ks)
        af[ct][ks] = *(const bf16x8*)(Ab + afo[ct][ks]);
    #pragma unroll
    for (int ct = 0; ct < 2; ++ct)
      #pragma unroll
      for (int m2 = 0; m2 < 2; ++m2){
        acc[ct][m2] = __builtin_amdgcn_mfma_f32_16x16x32_bf16(af[ct][0], pf[m2][0], acc[ct][m2], 0, 0, 0);
        acc[ct][m2] = __builtin_amdgcn_mfma_f32_16x16x32_bf16(af[ct][1], pf[m2][1], acc[ct][m2], 0, 0, 0);
      }
    __builtin_amdgcn_s_setprio(0);
  }
  #undef STAGEP

  // ---- epilogue: out[c][m] = gamma*acc + x1 (nontemporal both ways) ----
  const float g = gamma[0];
  const float* x1b = x1 + (size_t)b * C_ * W_;
  float* outb = out + (size_t)b * C_ * W_;
  #pragma unroll
  for (int ct = 0; ct < 2; ++ct)
    #pragma unroll
    for (int m2 = 0; m2 < 2; ++m2)
      #pragma unroll
      for (int r = 0; r < 4; ++r){
        const int c = wid * 32 + ct * 16 + lg * 4 + r;
        const size_t idx = (size_t)c * W_ + m0 + m2 * 16 + lr;
        const float xv = __builtin_nontemporal_load(&x1b[idx]);
        __builtin_nontemporal_store(fmaf(g, acc[ct][m2][r], xv), &outb[idx]);
      }
}

extern "C" void kernel_launch(void* const* d_in, const int* in_sizes, int n_in,
                              void* d_out, int out_size, void* d_ws, size_t ws_size,
                              hipStream_t stream)
{
  (void)in_sizes; (void)n_in; (void)out_size; (void)ws_size;
  const float* x0    = (const float*)d_in[0];
  const float* x1    = (const float*)d_in[1];
  const float* wq    = (const float*)d_in[2];
  const float* bq    = (const float*)d_in[3];
  const float* wk    = (const float*)d_in[4];
  const float* bk    = (const float*)d_in[5];
  const float* gamma = (const float*)d_in[6];

  unsigned short* qf  = (unsigned short*)d_ws;                   // 1 MB (fragment layout)
  unsigned short* kT  = qf + (size_t)B_ * W_ * DQK_;             // 1 MB
  unsigned short* x0t = kT + (size_t)B_ * W_ * DQK_;             // 8 MB swizzled tiles

  float* out = (float*)d_out;                                    // [B][C][W]
  float* att = out + (size_t)B_ * C_ * W_;                       // [B][W][W]

  sa_prep <<<dim3(128, 4), 512, 0, stream>>>(x0, x1, wq, bq, wk, bk, qf, kT, x0t);
  sa_fused<<<512, 512, 0, stream>>>(qf, kT, x0t, x1, gamma, out, att);
}